// Round 13
// baseline (337.616 us; speedup 1.0000x reference)
//
#include <hip/hip_runtime.h>

#define B_    2
#define S_    1024
#define H_    4096
#define NH_   32
#define DH_   128
#define NKV_  2
#define GROUP_ 16
#define ROT_  64
#define NQKV_ 4608   // NH*DH + 2*NKV*DH
#define SCALE_ 0.08838834764831845f  // 128^-0.5
#define KVB   64

typedef __attribute__((ext_vector_type(8))) short bf16x8;
typedef __attribute__((ext_vector_type(4))) float f32x4;

typedef __attribute__((address_space(1))) const void* gptr_t;
typedef __attribute__((address_space(3))) void* lptr_t;

__device__ __forceinline__ unsigned short f2bf(float f) {
    unsigned int u = __builtin_bit_cast(unsigned int, f);
    u += 0x7FFFu + ((u >> 16) & 1u);   // RNE
    return (unsigned short)(u >> 16);
}
__device__ __forceinline__ unsigned int pack2bf(float a, float b) {
    return (unsigned int)f2bf(a) | ((unsigned int)f2bf(b) << 16);
}

// ---------------- convert fp32 -> bf16 (vectorized) ----------------
__global__ void k_f32_to_bf16(const float* __restrict__ in,
                              unsigned short* __restrict__ out, int n4) {
    int i = blockIdx.x * blockDim.x + threadIdx.x;
    if (i >= n4) return;
    const float4 v = reinterpret_cast<const float4*>(in)[i];
    ushort4 o;
    o.x = f2bf(v.x); o.y = f2bf(v.y); o.z = f2bf(v.z); o.w = f2bf(v.w);
    reinterpret_cast<ushort4*>(out)[i] = o;
}

// ------- transpose fp32 [K][N] -> bf16 [N][K], 64x64 tile, vectorized ------
__global__ __launch_bounds__(256) void k_transpose_bf16(
    const float* __restrict__ in, unsigned short* __restrict__ out,
    int K, int N) {
    __shared__ float tile[64][69];
    const int n0 = blockIdx.x * 64, k0 = blockIdx.y * 64;
    const int t = threadIdx.x;
    const int lk = t >> 4, ln4 = (t & 15) * 4;
    #pragma unroll
    for (int i = 0; i < 4; i++) {
        const float4 v = *reinterpret_cast<const float4*>(
            in + (size_t)(k0 + lk + i * 16) * N + n0 + ln4);
        tile[lk + i * 16][ln4 + 0] = v.x;
        tile[lk + i * 16][ln4 + 1] = v.y;
        tile[lk + i * 16][ln4 + 2] = v.z;
        tile[lk + i * 16][ln4 + 3] = v.w;
    }
    __syncthreads();
    const int n = t >> 2, kc = (t & 3) * 16;
    unsigned short tmp[16];
    #pragma unroll
    for (int j = 0; j < 16; j++) tmp[j] = f2bf(tile[kc + j][n]);
    unsigned short* dst = out + (size_t)(n0 + n) * K + k0 + kc;
    *reinterpret_cast<uint4*>(dst)     = *reinterpret_cast<uint4*>(tmp);
    *reinterpret_cast<uint4*>(dst + 8) = *reinterpret_cast<uint4*>(tmp + 8);
}

// ------------- RoPE cos/sin table: tab[t][pr] = (cos, sin) ---------------
__global__ void k_rope_tab(const int* __restrict__ pos_ids,
                           float2* __restrict__ tab) {
    const int idx = blockIdx.x * blockDim.x + threadIdx.x;
    if (idx >= B_ * S_ * 32) return;
    const int t = idx >> 5, pr = idx & 31;
    const float freq = exp2f(-0.41524101186092f * (float)pr);
    float sn, cs;
    sincosf((float)pos_ids[t] * freq, &sn, &cs);
    tab[idx] = make_float2(cs, sn);
}

// ---- bf16 GEMM v9: 256x256, BK=64, 8 waves, m201 8-phase fine interleave --
// Per phase: {ds_read A-quadrant (+B at p0), issue 2 staging gload_lds of
// next K-tile (loads span 3 phase-barriers), raw barrier, setprio(1),
// 16 MFMA, setprio(0), barrier}. Single drain after p3's MFMA (all 8
// next-tile loads >=1 phase old). XOR-swizzled LDS both-sides (proven).
// C = A[M][K] * Bt[N][K]^T, fp32 out. Grid = nxt*8 (XCD-bijective, %8==0).
__global__ __launch_bounds__(512, 2) void k_gemm8(
    const unsigned short* __restrict__ A,
    const unsigned short* __restrict__ Bt,
    float* __restrict__ Cf,
    int M, int N, int K, int nxt)
{
    __shared__ __align__(16) char lds[2][65536];   // [buf][A 32KB | B 32KB]

    const int tid  = threadIdx.x;
    const int wave = tid >> 6, lane = tid & 63;
    const int lrow = lane & 15, lhi = lane >> 4;
    const int wm = wave >> 2, wn = wave & 3;       // 2 x 4 wave grid

    // bijective XCD swizzle (grid %8==0), column-major: same-XCD blocks share bx
    const int nwg = nxt * 8;
    const int cm = ((int)blockIdx.x & 7) * (nwg >> 3) + ((int)blockIdx.x >> 3);
    const int bx = cm >> 3, by = cm & 7;
    const size_t a_row0 = (size_t)by * 256;
    const size_t b_col0 = (size_t)bx * 256;

    const size_t strideK = (size_t)K * 2;          // bytes per row
    const char* Asrc = (const char*)A + (a_row0 + (tid >> 3)) * strideK;
    const char* Bsrc = (const char*)Bt + (b_col0 + (tid >> 3)) * strideK;
    const int swz_src = ((tid & 7) * 16) ^ (((tid >> 3) & 7) << 4);
    const int dst_off = tid * 16;

    f32x4 acc[8][4] = {};
    const int nt = K >> 6;   // BK=64

    // ---- prologue: stage K-tile 0 -> buf 0 (8 gloads/thread) ----
    #pragma unroll
    for (int j = 0; j < 4; j++) {
        __builtin_amdgcn_global_load_lds(
            (gptr_t)(Asrc + (size_t)(j * 64) * strideK + swz_src),
            (lptr_t)(lds[0] + j * 8192 + dst_off), 16, 0, 0);
        __builtin_amdgcn_global_load_lds(
            (gptr_t)(Bsrc + (size_t)(j * 64) * strideK + swz_src),
            (lptr_t)(lds[0] + 32768 + j * 8192 + dst_off), 16, 0, 0);
    }
    asm volatile("s_waitcnt vmcnt(0)" ::: "memory");
    __builtin_amdgcn_s_barrier();

    int cur = 0;
    for (int t = 0; t < nt; t++) {
        const char* La = lds[cur];
        const char* Lb = lds[cur] + 32768;
        const bool pre = (t + 1 < nt);
        const size_t kb = (size_t)(t + 1) * 128;   // BK=64 -> 128 B per tile
        bf16x8 bfr[4][2];
        #pragma unroll
        for (int p = 0; p < 4; p++) {
            // ---- ds_read this phase's A-quadrant (m-frags 2p, 2p+1) ----
            bf16x8 af[2][2];
            #pragma unroll
            for (int i = 0; i < 2; i++) {
                const int fr = wm * 128 + (p * 2 + i) * 16 + lrow;
                af[i][0] = *(const bf16x8*)(La + fr * 128 + ((lhi * 16) ^ ((fr & 7) << 4)));
                af[i][1] = *(const bf16x8*)(La + fr * 128 + ((64 + lhi * 16) ^ ((fr & 7) << 4)));
            }
            if (p == 0) {   // B-frags for the whole K-tile (held across phases)
                #pragma unroll
                for (int nf = 0; nf < 4; nf++) {
                    const int br = wn * 64 + nf * 16 + lrow;
                    bfr[nf][0] = *(const bf16x8*)(Lb + br * 128 + ((lhi * 16) ^ ((br & 7) << 4)));
                    bfr[nf][1] = *(const bf16x8*)(Lb + br * 128 + ((64 + lhi * 16) ^ ((br & 7) << 4)));
                }
            }
            // ---- stage 2 rounds of next tile into buf^1 (fine interleave) ----
            if (pre) {
                const char* src = (p < 2) ? Asrc : Bsrc;
                const int base  = (p < 2) ? 0 : 32768;
                #pragma unroll
                for (int j = 0; j < 2; j++) {
                    const int rr = (p & 1) * 2 + j;
                    __builtin_amdgcn_global_load_lds(
                        (gptr_t)(src + (size_t)(rr * 64) * strideK + kb + swz_src),
                        (lptr_t)(lds[cur ^ 1] + base + rr * 8192 + dst_off), 16, 0, 0);
                }
            }
            __builtin_amdgcn_s_barrier();
            __builtin_amdgcn_s_setprio(1);
            #pragma unroll
            for (int i = 0; i < 2; i++)
                #pragma unroll
                for (int nf = 0; nf < 4; nf++) {
                    acc[p * 2 + i][nf] = __builtin_amdgcn_mfma_f32_16x16x32_bf16(
                        af[i][0], bfr[nf][0], acc[p * 2 + i][nf], 0, 0, 0);
                    acc[p * 2 + i][nf] = __builtin_amdgcn_mfma_f32_16x16x32_bf16(
                        af[i][1], bfr[nf][1], acc[p * 2 + i][nf], 0, 0, 0);
                }
            __builtin_amdgcn_s_setprio(0);
            if (p == 3)   // all 8 next-tile loads issued >=1 phase ago: cheap drain
                asm volatile("s_waitcnt vmcnt(0)" ::: "memory");
            __builtin_amdgcn_s_barrier();
        }
        cur ^= 1;
    }

    // ---- epilogue: fp32 store (C/D: col=lane&15, row=lhi*4+r) ----
    #pragma unroll
    for (int mf = 0; mf < 8; mf++)
        #pragma unroll
        for (int nf = 0; nf < 4; nf++) {
            const size_t grow0 = a_row0 + wm * 128 + mf * 16 + lhi * 4;
            const size_t gcol  = b_col0 + wn * 64 + nf * 16 + lrow;
            #pragma unroll
            for (int r = 0; r < 4; r++)
                Cf[(grow0 + r) * N + gcol] = acc[mf][nf][r];
        }
}

// ------- QKV fuse: qkvF fp32 + bias + GLM RoPE (table) + head reorg --------
// qkvF [B*S][4608] -> Qh [B][NH][S][DH], Kh [B][NKV][S][DH], Vt [B][NKV][DH][S]
__global__ void k_qkv_fuse(const float* __restrict__ qkv,
                           const float* __restrict__ bias,
                           const float2* __restrict__ ctab,
                           unsigned short* __restrict__ Qh,
                           unsigned short* __restrict__ Kh,
                           unsigned short* __restrict__ Vt)
{
    const int NPR = (NH_ + 2 * NKV_) * 64;   // 2304 pair-units per token
    const int idx = blockIdx.x * blockDim.x + threadIdx.x;
    if (idx >= B_ * S_ * NPR) return;
    const int t = idx / NPR;
    const int rem = idx % NPR;
    const int unit = rem >> 6;
    const int pr = rem & 63;        // pair index: elems 2*pr, 2*pr+1
    const int b = t >> 10, s = t & 1023;
    const float* row = qkv + (size_t)t * NQKV_;

    if (unit < NH_ + NKV_) {        // Q or K head: rope on first 64 dims
        const int col = (unit < NH_) ? unit * DH_ + 2 * pr
                                     : NH_ * DH_ + (unit - NH_) * DH_ + 2 * pr;
        float x0 = row[col] + bias[col], x1 = row[col + 1] + bias[col + 1];
        if (pr < 32) {
            const float2 cs = ctab[t * 32 + pr];
            const float o0 = x0 * cs.x - x1 * cs.y;
            const float o1 = x1 * cs.x + x0 * cs.y;
            x0 = o0; x1 = o1;
        }
        unsigned short* dst = (unit < NH_)
            ? Qh + ((size_t)((b * NH_ + unit) * S_) + s) * DH_ + 2 * pr
            : Kh + ((size_t)((b * NKV_ + (unit - NH_)) * S_) + s) * DH_ + 2 * pr;
        *reinterpret_cast<unsigned int*>(dst) = pack2bf(x0, x1);
    } else {                        // V head -> transposed [DH][S]
        const int g = unit - NH_ - NKV_;
        const int col = NH_ * DH_ + NKV_ * DH_ + g * DH_ + 2 * pr;
        const float x0 = row[col] + bias[col];
        const float x1 = row[col + 1] + bias[col + 1];
        unsigned short* d0 = Vt + ((size_t)((b * NKV_ + g) * DH_) + 2 * pr) * S_ + s;
        d0[0]  = f2bf(x0);
        d0[S_] = f2bf(x1);
    }
}

// ------------- flash attention v3 (R9-proven): LDS-staged K/V, balanced ----
__global__ __launch_bounds__(256) void k_attn(
    const unsigned short* __restrict__ Qh,
    const unsigned short* __restrict__ Kh,
    const unsigned short* __restrict__ Vt,
    unsigned short* __restrict__ ctx)   // [B][S][NH*DH] bf16
{
    __shared__ __align__(16) char lds_kt[2][16384];  // K tile: 64 kv x 256B
    __shared__ __align__(16) char lds_vt[16384];     // V^T tile: 128 dh x 128B
    __shared__ __align__(16) char lds_p[4][2048];    // per-wave P: 16 q x 128B

    const int tid  = threadIdx.x;
    const int wave = tid >> 6, lane = tid & 63;
    const int lrow = lane & 15, lhi = lane >> 4;
    char* myp = lds_p[wave];

    const int blk  = blockIdx.x;
    const int pair = blk & 7;
    const int h    = (blk >> 3) & 31;
    const int b    = blk >> 8;
    const int g    = h >> 4;

    const char* Kbase = (const char*)(Kh + (size_t)((b * NKV_ + g) * S_) * DH_);
    const char* Vbase = (const char*)(Vt + (size_t)((b * NKV_ + g) * DH_) * S_);

    const int kcol = lrow * 16;          // K chunk: 4 rows x 256B, lane->row lhi
    const int vrow_l = lane >> 3;        // V chunk: 8 rows x 128B
    const int vcol = (lane & 7) * 16;

    for (int half = 0; half < 2; half++) {
        const int qt = half ? (15 - pair) : pair;
        const int q0 = qt * 64 + wave * 16;
        const int ntiles = qt + 1;
        const int q_glob = q0 + lrow;

        // ---- prologue: stage K[0] -> buf0; load Q frags ----
        #pragma unroll
        for (int i = 0; i < 4; i++) {
            const int ci = wave * 4 + i;
            const int r  = ci * 4 + lhi;
            __builtin_amdgcn_global_load_lds(
                (gptr_t)(Kbase + (size_t)r * 256 + (kcol ^ ((r & 7) << 4))),
                (lptr_t)(lds_kt[0] + ci * 1024), 16, 0, 0);
        }
        const unsigned short* Qp = Qh + ((size_t)((b * NH_ + h) * S_) + q0) * DH_;
        bf16x8 a_q[4];
        #pragma unroll
        for (int ks = 0; ks < 4; ks++)
            a_q[ks] = *(const bf16x8*)(Qp + (size_t)lrow * DH_ + ks * 32 + lhi * 8);
        asm volatile("s_waitcnt vmcnt(0)" ::: "memory");
        __builtin_amdgcn_s_barrier();

        float m_run = -1e30f, l_run = 0.f;
        f32x4 o_acc[8] = {};
        int cur = 0;

        for (int t = 0; t < ntiles; t++) {
            const bool has_next = (t + 1 < ntiles);
            #pragma unroll
            for (int i = 0; i < 4; i++) {
                const int ci = wave * 4 + i;
                const int r  = ci * 8 + vrow_l;
                __builtin_amdgcn_global_load_lds(
                    (gptr_t)(Vbase + (size_t)r * (S_ * 2) + t * (KVB * 2)
                             + (vcol ^ ((r & 7) << 4))),
                    (lptr_t)(lds_vt + ci * 1024), 16, 0, 0);
            }
            if (has_next) {
                const char* ksrc = Kbase + (size_t)(t + 1) * 16384;
                #pragma unroll
                for (int i = 0; i < 4; i++) {
                    const int ci = wave * 4 + i;
                    const int r  = ci * 4 + lhi;
                    __builtin_amdgcn_global_load_lds(
                        (gptr_t)(ksrc + (size_t)r * 256 + (kcol ^ ((r & 7) << 4))),
                        (lptr_t)(lds_kt[cur ^ 1] + ci * 1024), 16, 0, 0);
                }
            }
            f32x4 s_acc[4] = {};
            #pragma unroll
            for (int sub = 0; sub < 4; sub++) {
                const int r = sub * 16 + lrow;
                #pragma unroll
                for (int ks = 0; ks < 4; ks++) {
                    const bf16x8 a_k = *(const bf16x8*)(
                        lds_kt[cur] + r * 256 + ((ks * 64 + lhi * 16) ^ ((r & 7) << 4)));
                    s_acc[sub] = __builtin_amdgcn_mfma_f32_16x16x32_bf16(
                        a_k, a_q[ks], s_acc[sub], 0, 0, 0);
                }
            }
            float pv[16];
            float mx = -1e30f;
            if (!has_next) {
                #pragma unroll
                for (int sub = 0; sub < 4; sub++)
                    #pragma unroll
                    for (int r = 0; r < 4; r++) {
                        const int kvg = t * KVB + sub * 16 + lhi * 4 + r;
                        float sv = s_acc[sub][r] * SCALE_;
                        if (kvg > q_glob) sv = -1e30f;
                        pv[sub * 4 + r] = sv;
                        mx = fmaxf(mx, sv);
                    }
            } else {
                #pragma unroll
                for (int sub = 0; sub < 4; sub++)
                    #pragma unroll
                    for (int r = 0; r < 4; r++) {
                        const float sv = s_acc[sub][r] * SCALE_;
                        pv[sub * 4 + r] = sv;
                        mx = fmaxf(mx, sv);
                    }
            }
            mx = fmaxf(mx, __shfl_xor(mx, 16));
            mx = fmaxf(mx, __shfl_xor(mx, 32));
            const float mnew = fmaxf(m_run, mx);
            const float scale = __expf(m_run - mnew);
            m_run = mnew;
            float sm = 0.f;
            #pragma unroll
            for (int i = 0; i < 16; i++) {
                const float e = __expf(pv[i] - mnew);
                pv[i] = e;
                sm += e;
            }
            sm += __shfl_xor(sm, 16);
            sm += __shfl_xor(sm, 32);
            l_run = l_run * scale + sm;
            #pragma unroll
            for (int d = 0; d < 8; d++) {
                o_acc[d][0] *= scale; o_acc[d][1] *= scale;
                o_acc[d][2] *= scale; o_acc[d][3] *= scale;
            }
            #pragma unroll
            for (int sub = 0; sub < 4; sub++) {
                const int off = (lrow * 128 + sub * 32 + lhi * 8) ^ ((lrow & 7) << 4);
                *reinterpret_cast<uint2*>(myp + off) = make_uint2(
                    pack2bf(pv[sub * 4 + 0], pv[sub * 4 + 1]),
                    pack2bf(pv[sub * 4 + 2], pv[sub * 4 + 3]));
            }
            bf16x8 a_p[2];
            #pragma unroll
            for (int frag = 0; frag < 2; frag++) {
                const int off = (lrow * 128 + frag * 64 + lhi * 16) ^ ((lrow & 7) << 4);
                a_p[frag] = *reinterpret_cast<const bf16x8*>(myp + off);
            }
            if (has_next) asm volatile("s_waitcnt vmcnt(4)" ::: "memory");
            else          asm volatile("s_waitcnt vmcnt(0)" ::: "memory");
            __builtin_amdgcn_s_barrier();
            #pragma unroll
            for (int d = 0; d < 8; d++) {
                const int r = d * 16 + lrow;
                #pragma unroll
                for (int frag = 0; frag < 2; frag++) {
                    const bf16x8 a_v = *(const bf16x8*)(
                        lds_vt + r * 128 + ((frag * 64 + lhi * 16) ^ ((r & 7) << 4)));
                    o_acc[d] = __builtin_amdgcn_mfma_f32_16x16x32_bf16(
                        a_v, a_p[frag], o_acc[d], 0, 0, 0);
                }
            }
            asm volatile("s_waitcnt vmcnt(0)" ::: "memory");
            __builtin_amdgcn_s_barrier();
            cur ^= 1;
        }
        const float inv = 1.f / l_run;
        const size_t row = (size_t)b * S_ + q0 + lrow;
        #pragma unroll
        for (int d = 0; d < 8; d++) {
            unsigned short* dst = ctx + row * (NH_ * DH_) + h * DH_ + d * 16 + lhi * 4;
            *reinterpret_cast<uint2*>(dst) = make_uint2(
                pack2bf(o_acc[d][0] * inv, o_acc[d][1] * inv),
                pack2bf(o_acc[d][2] * inv, o_acc[d][3] * inv));
        }
    }
}

// --------------------------------------------------------------------------
extern "C" void kernel_launch(void* const* d_in, const int* in_sizes, int n_in,
                              void* d_out, int out_size, void* d_ws, size_t ws_size,
                              hipStream_t stream)
{
    const float* hidden  = (const float*)d_in[0];
    const int*   pos_ids = (const int*)d_in[1];
    const float* W_qkv   = (const float*)d_in[2];
    const float* b_qkv   = (const float*)d_in[3];
    const float* W_dense = (const float*)d_in[4];
    float* out = (float*)d_out;

    char* ws = (char*)d_ws;
    unsigned short* Xbf = (unsigned short*)(ws);                  // 16 MB
    unsigned short* Wqt = (unsigned short*)(ws + 16777216);       // 36 MB [4608][4096]
    unsigned short* Wdt = (unsigned short*)(ws + 54525952);       // 32 MB [4096][4096]
    float2*         ctab= (float2*)        (ws + 88080384);       // 512 KB [2048][32]
    float*          qkvF= (float*)         (ws + 88604672);       // 37.75 MB [2048][4608]
    unsigned short* Qh  = (unsigned short*)(ws + 126353408);      // 16 MB
    unsigned short* Kh  = (unsigned short*)(ws + 143130624);      //  1 MB
    unsigned short* Vt  = (unsigned short*)(ws + 144179200);      //  1 MB
    unsigned short* Ctx = (unsigned short*)(ws + 145227776);      // 16 MB

    const int M = B_ * S_;   // 2048

    // 1. hidden -> bf16; rope table
    k_f32_to_bf16<<<(M * H_ / 4 + 255) / 256, 256, 0, stream>>>(hidden, Xbf, M * H_ / 4);
    k_rope_tab<<<(M * 32 + 255) / 256, 256, 0, stream>>>(pos_ids, ctab);
    // 2. weight transposes (fp32 [K][N] -> bf16 [N][K]), 64x64 vectorized
    k_transpose_bf16<<<dim3(NQKV_ / 64, H_ / 64), 256, 0, stream>>>(W_qkv, Wqt, H_, NQKV_);
    k_transpose_bf16<<<dim3(H_ / 64, H_ / 64), 256, 0, stream>>>(W_dense, Wdt, H_, H_);
    // 3. QKV projection (8-phase 256² core) -> qkvF fp32; then fuse kernel
    k_gemm8<<<dim3((NQKV_ / 256) * 8), 512, 0, stream>>>(
        Xbf, Wqt, qkvF, M, NQKV_, H_, NQKV_ / 256);
    k_qkv_fuse<<<(M * 2304 + 255) / 256, 256, 0, stream>>>(
        qkvF, b_qkv, ctab, Qh, Kh, Vt);
    // 4. causal GQA attention -> ctx bf16 (512 blocks, 2/CU, balanced pairs)
    k_attn<<<B_ * NH_ * 8, 256, 0, stream>>>(Qh, Kh, Vt, Ctx);
    // 5. dense projection (8-phase 256² core) -> out fp32
    k_gemm8<<<dim3((H_ / 256) * 8), 512, 0, stream>>>(
        Ctx, Wdt, out, M, H_, H_, H_ / 256);
}

// Round 14
// 298.121 us; speedup vs baseline: 1.1325x; 1.1325x over previous
//
#include <hip/hip_runtime.h>

#define B_    2
#define S_    1024
#define H_    4096
#define NH_   32
#define DH_   128
#define NKV_  2
#define GROUP_ 16
#define ROT_  64
#define NQKV_ 4608   // NH*DH + 2*NKV*DH
#define SCALE_ 0.08838834764831845f  // 128^-0.5
#define KVB   64

typedef __attribute__((ext_vector_type(8))) short bf16x8;
typedef __attribute__((ext_vector_type(4))) float f32x4;

typedef __attribute__((address_space(1))) const void* gptr_t;
typedef __attribute__((address_space(3))) void* lptr_t;

__device__ __forceinline__ unsigned short f2bf(float f) {
    unsigned int u = __builtin_bit_cast(unsigned int, f);
    u += 0x7FFFu + ((u >> 16) & 1u);   // RNE
    return (unsigned short)(u >> 16);
}
__device__ __forceinline__ unsigned int pack2bf(float a, float b) {
    return (unsigned int)f2bf(a) | ((unsigned int)f2bf(b) << 16);
}

// ---------------- convert fp32 -> bf16 (vectorized) ----------------
__global__ void k_f32_to_bf16(const float* __restrict__ in,
                              unsigned short* __restrict__ out, int n4) {
    int i = blockIdx.x * blockDim.x + threadIdx.x;
    if (i >= n4) return;
    const float4 v = reinterpret_cast<const float4*>(in)[i];
    ushort4 o;
    o.x = f2bf(v.x); o.y = f2bf(v.y); o.z = f2bf(v.z); o.w = f2bf(v.w);
    reinterpret_cast<ushort4*>(out)[i] = o;
}

// ------- transpose fp32 [K][N] -> bf16 [N][K], 64x64 tile, vectorized ------
__global__ __launch_bounds__(256) void k_transpose_bf16(
    const float* __restrict__ in, unsigned short* __restrict__ out,
    int K, int N) {
    __shared__ float tile[64][69];
    const int n0 = blockIdx.x * 64, k0 = blockIdx.y * 64;
    const int t = threadIdx.x;
    const int lk = t >> 4, ln4 = (t & 15) * 4;
    #pragma unroll
    for (int i = 0; i < 4; i++) {
        const float4 v = *reinterpret_cast<const float4*>(
            in + (size_t)(k0 + lk + i * 16) * N + n0 + ln4);
        tile[lk + i * 16][ln4 + 0] = v.x;
        tile[lk + i * 16][ln4 + 1] = v.y;
        tile[lk + i * 16][ln4 + 2] = v.z;
        tile[lk + i * 16][ln4 + 3] = v.w;
    }
    __syncthreads();
    const int n = t >> 2, kc = (t & 3) * 16;
    unsigned short tmp[16];
    #pragma unroll
    for (int j = 0; j < 16; j++) tmp[j] = f2bf(tile[kc + j][n]);
    unsigned short* dst = out + (size_t)(n0 + n) * K + k0 + kc;
    *reinterpret_cast<uint4*>(dst)     = *reinterpret_cast<uint4*>(tmp);
    *reinterpret_cast<uint4*>(dst + 8) = *reinterpret_cast<uint4*>(tmp + 8);
}

// ------------- RoPE cos/sin table: tab[t][pr] = (cos, sin) ---------------
__global__ void k_rope_tab(const int* __restrict__ pos_ids,
                           float2* __restrict__ tab) {
    const int idx = blockIdx.x * blockDim.x + threadIdx.x;
    if (idx >= B_ * S_ * 32) return;
    const int t = idx >> 5, pr = idx & 31;
    const float freq = exp2f(-0.41524101186092f * (float)pr);
    float sn, cs;
    sincosf((float)pos_ids[t] * freq, &sn, &cs);
    tab[idx] = make_float2(cs, sn);
}

// -- bf16 GEMM v10: 128x128, BK=32 half-tiles, 4-slot LDS, counted vmcnt ----
// T4 pipeline (m218: counted-vs-drain = +38-73%): prefetch depth 3, per iter
// {vmcnt(8) [t landed, t+1/t+2 stay in flight ACROSS the barrier], barrier,
// issue stage t+3, 8 ds_read_b128, 16 MFMA}. vmcnt never 0 until the tail.
// Packed LDS layout: 2 rows (64B each) per 128B line, XOR (v&7)<<4 -> every
// consecutive-8-lane group covers all 8 bank slots (0-conflict on paper).
// MODE 0: C = A*Bt^T (+bias) fp32.  MODE 1: fused bias+RoPE(table)+reorg.
template<int MODE>
__global__ __launch_bounds__(256, 2) void k_gemm(
    const unsigned short* __restrict__ A,
    const unsigned short* __restrict__ Bt,
    const float* __restrict__ bias,
    float* __restrict__ Cf,
    const float2* __restrict__ ctab,
    unsigned short* __restrict__ Qh,
    unsigned short* __restrict__ Kh,
    unsigned short* __restrict__ Vt,
    int M, int N, int K)
{
    __shared__ __align__(16) char lds[4 * 16384];  // 4 slots: [A 8KB | B 8KB]

    const int tid  = threadIdx.x;
    const int wave = tid >> 6, lane = tid & 63;
    const int lrow = lane & 15, lhi = lane >> 4;
    const int wm = (wave >> 1) * 64, wn = (wave & 1) * 64;
    const size_t a_row0 = (size_t)blockIdx.y * 128;
    const size_t b_col0 = (size_t)blockIdx.x * 128;

    const size_t strideK = (size_t)K * 2;          // bytes per row
    const char* Abase = (const char*)A + a_row0 * strideK;
    const char* Bbase = (const char*)Bt + b_col0 * strideK;

    // staging source offset for 16B chunk q of the packed-swizzled tile:
    // phys byte q*16 -> v=q>>3, cp=(q&7)*16; cl=cp^((v&7)<<4);
    // row r = 2v + (cl>>6), in-row byte kb = cl&63.
    const int q0 = tid, q1 = tid + 256;
    const int v0_ = q0 >> 3, cl0 = ((q0 & 7) * 16) ^ ((v0_ & 7) << 4);
    const int v1_ = q1 >> 3, cl1 = ((q1 & 7) * 16) ^ ((v1_ & 7) << 4);
    const size_t aoff0 = (size_t)(v0_ * 2 + (cl0 >> 6)) * strideK + (cl0 & 63);
    const size_t aoff1 = (size_t)(v1_ * 2 + (cl1 >> 6)) * strideK + (cl1 & 63);

    f32x4 acc[4][4] = {};
    const int nt = K >> 5;   // BK=32 -> 64 bytes of K per tile

#define STAGE_(tt) { \
    const size_t kk = (size_t)(tt) * 64; \
    char* sl = lds + ((tt) & 3) * 16384; \
    __builtin_amdgcn_global_load_lds((gptr_t)(Abase + aoff0 + kk), \
        (lptr_t)(sl + tid * 16), 16, 0, 0); \
    __builtin_amdgcn_global_load_lds((gptr_t)(Abase + aoff1 + kk), \
        (lptr_t)(sl + 4096 + tid * 16), 16, 0, 0); \
    __builtin_amdgcn_global_load_lds((gptr_t)(Bbase + aoff0 + kk), \
        (lptr_t)(sl + 8192 + tid * 16), 16, 0, 0); \
    __builtin_amdgcn_global_load_lds((gptr_t)(Bbase + aoff1 + kk), \
        (lptr_t)(sl + 12288 + tid * 16), 16, 0, 0); }

    // ---- prologue: stage tiles 0,1,2 (12 loads in flight) ----
    STAGE_(0);
    if (1 < nt) STAGE_(1);
    if (2 < nt) STAGE_(2);

    for (int t = 0; t < nt; t++) {
        // counted wait: tile t landed; deeper prefetches stay in flight
        if (t + 2 < nt)      asm volatile("s_waitcnt vmcnt(8)" ::: "memory");
        else if (t + 1 < nt) asm volatile("s_waitcnt vmcnt(4)" ::: "memory");
        else                 asm volatile("s_waitcnt vmcnt(0)" ::: "memory");
        __builtin_amdgcn_s_barrier();
        if (t + 3 < nt) STAGE_(t + 3);   // into slot (t+3)&3 == (t-1)&3 (free)

        const char* sA = lds + (t & 3) * 16384;
        const char* sB = sA + 8192;
        bf16x8 af[4], bfr[4];
        #pragma unroll
        for (int mi = 0; mi < 4; mi++) {
            const int r = wm + mi * 16 + lrow;
            const int v = r >> 1;
            const int cl = ((r & 1) << 6) + (lhi << 4);
            af[mi] = *(const bf16x8*)(sA + v * 128 + (cl ^ ((v & 7) << 4)));
        }
        #pragma unroll
        for (int nj = 0; nj < 4; nj++) {
            const int r = wn + nj * 16 + lrow;
            const int v = r >> 1;
            const int cl = ((r & 1) << 6) + (lhi << 4);
            bfr[nj] = *(const bf16x8*)(sB + v * 128 + (cl ^ ((v & 7) << 4)));
        }
        #pragma unroll
        for (int mi = 0; mi < 4; mi++)
            #pragma unroll
            for (int nj = 0; nj < 4; nj++)
                acc[mi][nj] = __builtin_amdgcn_mfma_f32_16x16x32_bf16(
                    af[mi], bfr[nj], acc[mi][nj], 0, 0, 0);
    }
#undef STAGE_

    // ---- epilogue (C/D layout: col = lane&15, row = lhi*4 + r) ----
    if (MODE == 0) {
        #pragma unroll
        for (int i = 0; i < 4; i++)
            #pragma unroll
            for (int j = 0; j < 4; j++) {
                const size_t grow0 = a_row0 + wm + i * 16 + lhi * 4;
                const size_t gcol  = b_col0 + wn + j * 16 + lrow;
                const float bi = bias ? bias[gcol] : 0.f;
                #pragma unroll
                for (int r = 0; r < 4; r++)
                    Cf[(grow0 + r) * N + gcol] = acc[i][j][r] + bi;
            }
    } else {
        const int bx = (int)blockIdx.x;
        const size_t bb = a_row0 >> 10;            // batch (tile never crosses)
        if (bx >= 34) {
            // V head -> transposed [DH][S]; lane holds 4 consecutive s (8B store)
            const int g = bx - 34;
            #pragma unroll
            for (int i = 0; i < 4; i++)
                #pragma unroll
                for (int j = 0; j < 4; j++) {
                    const int dloc = wn + j * 16 + lrow;
                    const float bi = bias[b_col0 + dloc];
                    const size_t row0 = a_row0 + wm + i * 16 + lhi * 4;
                    unsigned short* dst =
                        Vt + ((bb * NKV_ + g) * DH_ + dloc) * S_ + (row0 & 1023);
                    *reinterpret_cast<uint2*>(dst) = make_uint2(
                        pack2bf(acc[i][j][0] + bi, acc[i][j][1] + bi),
                        pack2bf(acc[i][j][2] + bi, acc[i][j][3] + bi));
                }
        } else {
            // Q (bx<32) / K (bx 32,33): rope via table, LDS-staged coalesced out
            __syncthreads();                       // done reading K-loop slots
            unsigned short* lds_c = (unsigned short*)&lds[0];  // 32 KB tile
            #pragma unroll
            for (int i = 0; i < 4; i++)
                #pragma unroll
                for (int j = 0; j < 4; j++) {
                    const int dloc = wn + j * 16 + lrow;
                    const float bi = bias[b_col0 + dloc];
                    const int rloc0 = wm + i * 16 + lhi * 4;
                    float v[4];
                    #pragma unroll
                    for (int r = 0; r < 4; r++) v[r] = acc[i][j][r] + bi;
                    if (dloc < 64) {               // wave-uniform (wn==0)
                        const int pr = dloc >> 1;
                        #pragma unroll
                        for (int r = 0; r < 4; r++) {
                            const float2 cs = ctab[(a_row0 + rloc0 + r) * 32 + pr];
                            const float partner = __shfl_xor(v[r], 1);
                            v[r] = (dloc & 1) ? (v[r] * cs.x + partner * cs.y)
                                              : (v[r] * cs.x - partner * cs.y);
                        }
                    }
                    #pragma unroll
                    for (int r = 0; r < 4; r++)
                        lds_c[(rloc0 + r) * 128 + dloc] = f2bf(v[r]);
                }
            __syncthreads();
            unsigned short* base = (bx < 32)
                ? Qh + ((bb * NH_ + bx) * S_ + (a_row0 & 1023)) * DH_
                : Kh + ((bb * NKV_ + (bx - 32)) * S_ + (a_row0 & 1023)) * DH_;
            const int off = tid * 64;              // 64 ushorts = 128 B / thread
            #pragma unroll
            for (int c = 0; c < 8; c++)
                *reinterpret_cast<uint4*>(base + off + c * 8) =
                    *reinterpret_cast<const uint4*>(lds_c + off + c * 8);
        }
    }
}

// ------------- flash attention v3 (R9-proven): LDS-staged K/V, balanced ----
__global__ __launch_bounds__(256) void k_attn(
    const unsigned short* __restrict__ Qh,
    const unsigned short* __restrict__ Kh,
    const unsigned short* __restrict__ Vt,
    unsigned short* __restrict__ ctx)   // [B][S][NH*DH] bf16
{
    __shared__ __align__(16) char lds_kt[2][16384];  // K tile: 64 kv x 256B
    __shared__ __align__(16) char lds_vt[16384];     // V^T tile: 128 dh x 128B
    __shared__ __align__(16) char lds_p[4][2048];    // per-wave P: 16 q x 128B

    const int tid  = threadIdx.x;
    const int wave = tid >> 6, lane = tid & 63;
    const int lrow = lane & 15, lhi = lane >> 4;
    char* myp = lds_p[wave];

    const int blk  = blockIdx.x;
    const int pair = blk & 7;
    const int h    = (blk >> 3) & 31;
    const int b    = blk >> 8;
    const int g    = h >> 4;

    const char* Kbase = (const char*)(Kh + (size_t)((b * NKV_ + g) * S_) * DH_);
    const char* Vbase = (const char*)(Vt + (size_t)((b * NKV_ + g) * DH_) * S_);

    const int kcol = lrow * 16;          // K chunk: 4 rows x 256B, lane->row lhi
    const int vrow_l = lane >> 3;        // V chunk: 8 rows x 128B
    const int vcol = (lane & 7) * 16;

    for (int half = 0; half < 2; half++) {
        const int qt = half ? (15 - pair) : pair;
        const int q0 = qt * 64 + wave * 16;
        const int ntiles = qt + 1;
        const int q_glob = q0 + lrow;

        // ---- prologue: stage K[0] -> buf0; load Q frags ----
        #pragma unroll
        for (int i = 0; i < 4; i++) {
            const int ci = wave * 4 + i;
            const int r  = ci * 4 + lhi;
            __builtin_amdgcn_global_load_lds(
                (gptr_t)(Kbase + (size_t)r * 256 + (kcol ^ ((r & 7) << 4))),
                (lptr_t)(lds_kt[0] + ci * 1024), 16, 0, 0);
        }
        const unsigned short* Qp = Qh + ((size_t)((b * NH_ + h) * S_) + q0) * DH_;
        bf16x8 a_q[4];
        #pragma unroll
        for (int ks = 0; ks < 4; ks++)
            a_q[ks] = *(const bf16x8*)(Qp + (size_t)lrow * DH_ + ks * 32 + lhi * 8);
        asm volatile("s_waitcnt vmcnt(0)" ::: "memory");
        __builtin_amdgcn_s_barrier();

        float m_run = -1e30f, l_run = 0.f;
        f32x4 o_acc[8] = {};
        int cur = 0;

        for (int t = 0; t < ntiles; t++) {
            const bool has_next = (t + 1 < ntiles);
            #pragma unroll
            for (int i = 0; i < 4; i++) {
                const int ci = wave * 4 + i;
                const int r  = ci * 8 + vrow_l;
                __builtin_amdgcn_global_load_lds(
                    (gptr_t)(Vbase + (size_t)r * (S_ * 2) + t * (KVB * 2)
                             + (vcol ^ ((r & 7) << 4))),
                    (lptr_t)(lds_vt + ci * 1024), 16, 0, 0);
            }
            if (has_next) {
                const char* ksrc = Kbase + (size_t)(t + 1) * 16384;
                #pragma unroll
                for (int i = 0; i < 4; i++) {
                    const int ci = wave * 4 + i;
                    const int r  = ci * 4 + lhi;
                    __builtin_amdgcn_global_load_lds(
                        (gptr_t)(ksrc + (size_t)r * 256 + (kcol ^ ((r & 7) << 4))),
                        (lptr_t)(lds_kt[cur ^ 1] + ci * 1024), 16, 0, 0);
                }
            }
            f32x4 s_acc[4] = {};
            #pragma unroll
            for (int sub = 0; sub < 4; sub++) {
                const int r = sub * 16 + lrow;
                #pragma unroll
                for (int ks = 0; ks < 4; ks++) {
                    const bf16x8 a_k = *(const bf16x8*)(
                        lds_kt[cur] + r * 256 + ((ks * 64 + lhi * 16) ^ ((r & 7) << 4)));
                    s_acc[sub] = __builtin_amdgcn_mfma_f32_16x16x32_bf16(
                        a_k, a_q[ks], s_acc[sub], 0, 0, 0);
                }
            }
            float pv[16];
            float mx = -1e30f;
            if (!has_next) {
                #pragma unroll
                for (int sub = 0; sub < 4; sub++)
                    #pragma unroll
                    for (int r = 0; r < 4; r++) {
                        const int kvg = t * KVB + sub * 16 + lhi * 4 + r;
                        float sv = s_acc[sub][r] * SCALE_;
                        if (kvg > q_glob) sv = -1e30f;
                        pv[sub * 4 + r] = sv;
                        mx = fmaxf(mx, sv);
                    }
            } else {
                #pragma unroll
                for (int sub = 0; sub < 4; sub++)
                    #pragma unroll
                    for (int r = 0; r < 4; r++) {
                        const float sv = s_acc[sub][r] * SCALE_;
                        pv[sub * 4 + r] = sv;
                        mx = fmaxf(mx, sv);
                    }
            }
            mx = fmaxf(mx, __shfl_xor(mx, 16));
            mx = fmaxf(mx, __shfl_xor(mx, 32));
            const float mnew = fmaxf(m_run, mx);
            const float scale = __expf(m_run - mnew);
            m_run = mnew;
            float sm = 0.f;
            #pragma unroll
            for (int i = 0; i < 16; i++) {
                const float e = __expf(pv[i] - mnew);
                pv[i] = e;
                sm += e;
            }
            sm += __shfl_xor(sm, 16);
            sm += __shfl_xor(sm, 32);
            l_run = l_run * scale + sm;
            #pragma unroll
            for (int d = 0; d < 8; d++) {
                o_acc[d][0] *= scale; o_acc[d][1] *= scale;
                o_acc[d][2] *= scale; o_acc[d][3] *= scale;
            }
            #pragma unroll
            for (int sub = 0; sub < 4; sub++) {
                const int off = (lrow * 128 + sub * 32 + lhi * 8) ^ ((lrow & 7) << 4);
                *reinterpret_cast<uint2*>(myp + off) = make_uint2(
                    pack2bf(pv[sub * 4 + 0], pv[sub * 4 + 1]),
                    pack2bf(pv[sub * 4 + 2], pv[sub * 4 + 3]));
            }
            bf16x8 a_p[2];
            #pragma unroll
            for (int frag = 0; frag < 2; frag++) {
                const int off = (lrow * 128 + frag * 64 + lhi * 16) ^ ((lrow & 7) << 4);
                a_p[frag] = *reinterpret_cast<const bf16x8*>(myp + off);
            }
            if (has_next) asm volatile("s_waitcnt vmcnt(4)" ::: "memory");
            else          asm volatile("s_waitcnt vmcnt(0)" ::: "memory");
            __builtin_amdgcn_s_barrier();
            #pragma unroll
            for (int d = 0; d < 8; d++) {
                const int r = d * 16 + lrow;
                #pragma unroll
                for (int frag = 0; frag < 2; frag++) {
                    const bf16x8 a_v = *(const bf16x8*)(
                        lds_vt + r * 128 + ((frag * 64 + lhi * 16) ^ ((r & 7) << 4)));
                    o_acc[d] = __builtin_amdgcn_mfma_f32_16x16x32_bf16(
                        a_v, a_p[frag], o_acc[d], 0, 0, 0);
                }
            }
            asm volatile("s_waitcnt vmcnt(0)" ::: "memory");
            __builtin_amdgcn_s_barrier();
            cur ^= 1;
        }
        const float inv = 1.f / l_run;
        const size_t row = (size_t)b * S_ + q0 + lrow;
        #pragma unroll
        for (int d = 0; d < 8; d++) {
            unsigned short* dst = ctx + row * (NH_ * DH_) + h * DH_ + d * 16 + lhi * 4;
            *reinterpret_cast<uint2*>(dst) = make_uint2(
                pack2bf(o_acc[d][0] * inv, o_acc[d][1] * inv),
                pack2bf(o_acc[d][2] * inv, o_acc[d][3] * inv));
        }
    }
}

// --------------------------------------------------------------------------
extern "C" void kernel_launch(void* const* d_in, const int* in_sizes, int n_in,
                              void* d_out, int out_size, void* d_ws, size_t ws_size,
                              hipStream_t stream)
{
    const float* hidden  = (const float*)d_in[0];
    const int*   pos_ids = (const int*)d_in[1];
    const float* W_qkv   = (const float*)d_in[2];
    const float* b_qkv   = (const float*)d_in[3];
    const float* W_dense = (const float*)d_in[4];
    float* out = (float*)d_out;

    char* ws = (char*)d_ws;
    unsigned short* Xbf = (unsigned short*)(ws);                  // 16 MB
    unsigned short* Wqt = (unsigned short*)(ws + 16777216);       // 36 MB [4608][4096]
    unsigned short* Wdt = (unsigned short*)(ws + 54525952);       // 32 MB [4096][4096]
    float2*         ctab= (float2*)        (ws + 88080384);       // 512 KB [2048][32]
    unsigned short* Qh  = (unsigned short*)(ws + 125829120);      // 16 MB
    unsigned short* Kh  = (unsigned short*)(ws + 142606336);      //  1 MB
    unsigned short* Vt  = (unsigned short*)(ws + 143654912);      //  1 MB
    unsigned short* Ctx = (unsigned short*)(ws + 144703488);      // 16 MB

    const int M = B_ * S_;   // 2048

    // 1. hidden -> bf16; rope table
    k_f32_to_bf16<<<(M * H_ / 4 + 255) / 256, 256, 0, stream>>>(hidden, Xbf, M * H_ / 4);
    k_rope_tab<<<(M * 32 + 255) / 256, 256, 0, stream>>>(pos_ids, ctab);
    // 2. weight transposes (fp32 [K][N] -> bf16 [N][K]), 64x64 vectorized
    k_transpose_bf16<<<dim3(NQKV_ / 64, H_ / 64), 256, 0, stream>>>(W_qkv, Wqt, H_, NQKV_);
    k_transpose_bf16<<<dim3(H_ / 64, H_ / 64), 256, 0, stream>>>(W_dense, Wdt, H_, H_);
    // 3. QKV projection + fused bias/RoPE/reorg -> Qh, Kh, Vt
    k_gemm<1><<<dim3(NQKV_ / 128, M / 128), 256, 0, stream>>>(
        Xbf, Wqt, b_qkv, nullptr, ctab, Qh, Kh, Vt, M, NQKV_, H_);
    // 4. causal GQA attention -> ctx bf16 (512 blocks, 2/CU, balanced pairs)
    k_attn<<<B_ * NH_ * 8, 256, 0, stream>>>(Qh, Kh, Vt, Ctx);
    // 5. dense projection: out = ctx @ W_dense
    k_gemm<0><<<dim3(H_ / 128, M / 128), 256, 0, stream>>>(
        Ctx, Wdt, nullptr, out, nullptr, nullptr, nullptr, nullptr, M, H_, H_);
}

// Round 15
// 269.490 us; speedup vs baseline: 1.2528x; 1.1062x over previous
//
#include <hip/hip_runtime.h>

#define B_    2
#define S_    1024
#define H_    4096
#define NH_   32
#define DH_   128
#define NKV_  2
#define GROUP_ 16
#define ROT_  64
#define NQKV_ 4608   // NH*DH + 2*NKV*DH
#define SCALE_ 0.08838834764831845f  // 128^-0.5
#define KVB   64

typedef __attribute__((ext_vector_type(8))) short bf16x8;
typedef __attribute__((ext_vector_type(4))) float f32x4;

typedef __attribute__((address_space(1))) const void* gptr_t;
typedef __attribute__((address_space(3))) void* lptr_t;

__device__ __forceinline__ unsigned short f2bf(float f) {
    unsigned int u = __builtin_bit_cast(unsigned int, f);
    u += 0x7FFFu + ((u >> 16) & 1u);   // RNE
    return (unsigned short)(u >> 16);
}
__device__ __forceinline__ unsigned int pack2bf(float a, float b) {
    return (unsigned int)f2bf(a) | ((unsigned int)f2bf(b) << 16);
}

// ---------------- convert fp32 -> bf16 (vectorized) ----------------
__global__ void k_f32_to_bf16(const float* __restrict__ in,
                              unsigned short* __restrict__ out, int n4) {
    int i = blockIdx.x * blockDim.x + threadIdx.x;
    if (i >= n4) return;
    const float4 v = reinterpret_cast<const float4*>(in)[i];
    ushort4 o;
    o.x = f2bf(v.x); o.y = f2bf(v.y); o.z = f2bf(v.z); o.w = f2bf(v.w);
    reinterpret_cast<ushort4*>(out)[i] = o;
}

// ------- transpose fp32 [K][N] -> bf16 [N][K], 64x64 tile, vectorized ------
__global__ __launch_bounds__(256) void k_transpose_bf16(
    const float* __restrict__ in, unsigned short* __restrict__ out,
    int K, int N) {
    __shared__ float tile[64][69];
    const int n0 = blockIdx.x * 64, k0 = blockIdx.y * 64;
    const int t = threadIdx.x;
    const int lk = t >> 4, ln4 = (t & 15) * 4;
    #pragma unroll
    for (int i = 0; i < 4; i++) {
        const float4 v = *reinterpret_cast<const float4*>(
            in + (size_t)(k0 + lk + i * 16) * N + n0 + ln4);
        tile[lk + i * 16][ln4 + 0] = v.x;
        tile[lk + i * 16][ln4 + 1] = v.y;
        tile[lk + i * 16][ln4 + 2] = v.z;
        tile[lk + i * 16][ln4 + 3] = v.w;
    }
    __syncthreads();
    const int n = t >> 2, kc = (t & 3) * 16;
    unsigned short tmp[16];
    #pragma unroll
    for (int j = 0; j < 16; j++) tmp[j] = f2bf(tile[kc + j][n]);
    unsigned short* dst = out + (size_t)(n0 + n) * K + k0 + kc;
    *reinterpret_cast<uint4*>(dst)     = *reinterpret_cast<uint4*>(tmp);
    *reinterpret_cast<uint4*>(dst + 8) = *reinterpret_cast<uint4*>(tmp + 8);
}

// ------------- RoPE cos/sin table: tab[t][pr] = (cos, sin) ---------------
__global__ void k_rope_tab(const int* __restrict__ pos_ids,
                           float2* __restrict__ tab) {
    const int idx = blockIdx.x * blockDim.x + threadIdx.x;
    if (idx >= B_ * S_ * 32) return;
    const int t = idx >> 5, pr = idx & 31;
    const float freq = exp2f(-0.41524101186092f * (float)pr);
    float sn, cs;
    sincosf((float)pos_ids[t] * freq, &sn, &cs);
    tab[idx] = make_float2(cs, sn);
}

// ------------- bf16 GEMM (R9/R12-measured): 128x128, BK=64, 2 blocks/CU ----
// MODE 0: C = A*Bt^T (+bias) fp32 out.
// MODE 1: QKV projection, fused bias + GLM RoPE (table) + head reorg.
template<int MODE>
__global__ __launch_bounds__(256, 2) void k_gemm(
    const unsigned short* __restrict__ A,
    const unsigned short* __restrict__ Bt,
    const float* __restrict__ bias,
    float* __restrict__ Cf,
    const float2* __restrict__ ctab,
    unsigned short* __restrict__ Qh,
    unsigned short* __restrict__ Kh,
    unsigned short* __restrict__ Vt,
    int M, int N, int K)
{
    __shared__ __align__(16) char lds[2][32768];   // [buf][A 16KB | B 16KB]

    const int tid  = threadIdx.x;
    const int wave = tid >> 6, lane = tid & 63;
    const int lrow = lane & 15, lhi = lane >> 4;
    const int wm = (wave >> 1) * 64, wn = (wave & 1) * 64;
    const size_t a_row0 = (size_t)blockIdx.y * 128;
    const size_t b_col0 = (size_t)blockIdx.x * 128;

    const size_t strideK = (size_t)K * 2;          // bytes per row
    const char* Asrc = (const char*)A + (a_row0 + (tid >> 3)) * strideK;
    const char* Bsrc = (const char*)Bt + (b_col0 + (tid >> 3)) * strideK;
    const int swz_src = ((tid & 7) * 16) ^ (((tid >> 3) & 7) << 4);
    const int dst_off = tid * 16;

    f32x4 acc[4][4] = {};
    const int nt = K >> 6;   // BK=64

    #pragma unroll
    for (int j = 0; j < 4; j++) {
        __builtin_amdgcn_global_load_lds(
            (gptr_t)(Asrc + (size_t)j * 32 * strideK + swz_src),
            (lptr_t)(lds[0] + j * 4096 + dst_off), 16, 0, 0);
        __builtin_amdgcn_global_load_lds(
            (gptr_t)(Bsrc + (size_t)j * 32 * strideK + swz_src),
            (lptr_t)(lds[0] + 16384 + j * 4096 + dst_off), 16, 0, 0);
    }

    int cur = 0;
    for (int t = 0; t < nt; t++) {
        if (t + 1 < nt) {
            const size_t kb = (size_t)(t + 1) * 128;   // BK=64 -> 128 bytes
            #pragma unroll
            for (int j = 0; j < 4; j++) {
                __builtin_amdgcn_global_load_lds(
                    (gptr_t)(Asrc + (size_t)j * 32 * strideK + kb + swz_src),
                    (lptr_t)(lds[cur ^ 1] + j * 4096 + dst_off), 16, 0, 0);
                __builtin_amdgcn_global_load_lds(
                    (gptr_t)(Bsrc + (size_t)j * 32 * strideK + kb + swz_src),
                    (lptr_t)(lds[cur ^ 1] + 16384 + j * 4096 + dst_off), 16, 0, 0);
            }
            asm volatile("s_waitcnt vmcnt(8)" ::: "memory");   // tile t landed
        } else {
            asm volatile("s_waitcnt vmcnt(0)" ::: "memory");
        }
        __builtin_amdgcn_s_barrier();

        const char* La = lds[cur];
        const char* Lb = lds[cur] + 16384;
        bf16x8 af[4][2], bfr[4][2];
        #pragma unroll
        for (int i = 0; i < 4; i++) {
            const int fr = wm + i * 16 + lrow;
            af[i][0] = *(const bf16x8*)(La + fr * 128 + ((lhi * 16) ^ ((fr & 7) << 4)));
            af[i][1] = *(const bf16x8*)(La + fr * 128 + ((64 + lhi * 16) ^ ((fr & 7) << 4)));
        }
        #pragma unroll
        for (int j = 0; j < 4; j++) {
            const int br = wn + j * 16 + lrow;
            bfr[j][0] = *(const bf16x8*)(Lb + br * 128 + ((lhi * 16) ^ ((br & 7) << 4)));
            bfr[j][1] = *(const bf16x8*)(Lb + br * 128 + ((64 + lhi * 16) ^ ((br & 7) << 4)));
        }
        #pragma unroll
        for (int i = 0; i < 4; i++)
            #pragma unroll
            for (int j = 0; j < 4; j++) {
                acc[i][j] = __builtin_amdgcn_mfma_f32_16x16x32_bf16(
                    af[i][0], bfr[j][0], acc[i][j], 0, 0, 0);
                acc[i][j] = __builtin_amdgcn_mfma_f32_16x16x32_bf16(
                    af[i][1], bfr[j][1], acc[i][j], 0, 0, 0);
            }
        __builtin_amdgcn_s_barrier();
        cur ^= 1;
    }

    // ---- epilogue (C/D layout: col = lane&15, row = lhi*4 + r) ----
    if (MODE == 0) {
        #pragma unroll
        for (int i = 0; i < 4; i++)
            #pragma unroll
            for (int j = 0; j < 4; j++) {
                const size_t grow0 = a_row0 + wm + i * 16 + lhi * 4;
                const size_t gcol  = b_col0 + wn + j * 16 + lrow;
                const float bi = bias ? bias[gcol] : 0.f;
                #pragma unroll
                for (int r = 0; r < 4; r++)
                    Cf[(grow0 + r) * N + gcol] = acc[i][j][r] + bi;
            }
    } else {
        const int bx = (int)blockIdx.x;
        const size_t bb = a_row0 >> 10;            // batch (tile never crosses)
        if (bx >= 34) {
            // V head -> transposed [DH][S]; lane holds 4 consecutive s (8B store)
            const int g = bx - 34;
            #pragma unroll
            for (int i = 0; i < 4; i++)
                #pragma unroll
                for (int j = 0; j < 4; j++) {
                    const int dloc = wn + j * 16 + lrow;
                    const float bi = bias[b_col0 + dloc];
                    const size_t row0 = a_row0 + wm + i * 16 + lhi * 4;
                    unsigned short* dst =
                        Vt + ((bb * NKV_ + g) * DH_ + dloc) * S_ + (row0 & 1023);
                    *reinterpret_cast<uint2*>(dst) = make_uint2(
                        pack2bf(acc[i][j][0] + bi, acc[i][j][1] + bi),
                        pack2bf(acc[i][j][2] + bi, acc[i][j][3] + bi));
                }
        } else {
            // Q (bx<32) / K (bx 32,33): rope via table, LDS-staged coalesced out
            unsigned short* lds_c = (unsigned short*)&lds[0][0];  // 32 KB tile
            #pragma unroll
            for (int i = 0; i < 4; i++)
                #pragma unroll
                for (int j = 0; j < 4; j++) {
                    const int dloc = wn + j * 16 + lrow;
                    const float bi = bias[b_col0 + dloc];
                    const int rloc0 = wm + i * 16 + lhi * 4;
                    float v[4];
                    #pragma unroll
                    for (int r = 0; r < 4; r++) v[r] = acc[i][j][r] + bi;
                    if (dloc < 64) {               // wave-uniform (wn==0)
                        const int pr = dloc >> 1;
                        #pragma unroll
                        for (int r = 0; r < 4; r++) {
                            const float2 cs = ctab[(a_row0 + rloc0 + r) * 32 + pr];
                            const float partner = __shfl_xor(v[r], 1);
                            v[r] = (dloc & 1) ? (v[r] * cs.x + partner * cs.y)
                                              : (v[r] * cs.x - partner * cs.y);
                        }
                    }
                    #pragma unroll
                    for (int r = 0; r < 4; r++)
                        lds_c[(rloc0 + r) * 128 + dloc] = f2bf(v[r]);
                }
            __syncthreads();
            unsigned short* base = (bx < 32)
                ? Qh + ((bb * NH_ + bx) * S_ + (a_row0 & 1023)) * DH_
                : Kh + ((bb * NKV_ + (bx - 32)) * S_ + (a_row0 & 1023)) * DH_;
            const int off = tid * 64;              // 64 ushorts = 128 B / thread
            #pragma unroll
            for (int c = 0; c < 8; c++)
                *reinterpret_cast<uint4*>(base + off + c * 8) =
                    *reinterpret_cast<const uint4*>(lds_c + off + c * 8);
        }
    }
}

// ------------- flash attention v3 (R9-proven): LDS-staged K/V, balanced ----
__global__ __launch_bounds__(256) void k_attn(
    const unsigned short* __restrict__ Qh,
    const unsigned short* __restrict__ Kh,
    const unsigned short* __restrict__ Vt,
    unsigned short* __restrict__ ctx)   // [B][S][NH*DH] bf16
{
    __shared__ __align__(16) char lds_kt[2][16384];  // K tile: 64 kv x 256B
    __shared__ __align__(16) char lds_vt[16384];     // V^T tile: 128 dh x 128B
    __shared__ __align__(16) char lds_p[4][2048];    // per-wave P: 16 q x 128B

    const int tid  = threadIdx.x;
    const int wave = tid >> 6, lane = tid & 63;
    const int lrow = lane & 15, lhi = lane >> 4;
    char* myp = lds_p[wave];

    const int blk  = blockIdx.x;
    const int pair = blk & 7;
    const int h    = (blk >> 3) & 31;
    const int b    = blk >> 8;
    const int g    = h >> 4;

    const char* Kbase = (const char*)(Kh + (size_t)((b * NKV_ + g) * S_) * DH_);
    const char* Vbase = (const char*)(Vt + (size_t)((b * NKV_ + g) * DH_) * S_);

    const int kcol = lrow * 16;          // K chunk: 4 rows x 256B, lane->row lhi
    const int vrow_l = lane >> 3;        // V chunk: 8 rows x 128B
    const int vcol = (lane & 7) * 16;

    for (int half = 0; half < 2; half++) {
        const int qt = half ? (15 - pair) : pair;
        const int q0 = qt * 64 + wave * 16;
        const int ntiles = qt + 1;
        const int q_glob = q0 + lrow;

        // ---- prologue: stage K[0] -> buf0; load Q frags ----
        #pragma unroll
        for (int i = 0; i < 4; i++) {
            const int ci = wave * 4 + i;
            const int r  = ci * 4 + lhi;
            __builtin_amdgcn_global_load_lds(
                (gptr_t)(Kbase + (size_t)r * 256 + (kcol ^ ((r & 7) << 4))),
                (lptr_t)(lds_kt[0] + ci * 1024), 16, 0, 0);
        }
        const unsigned short* Qp = Qh + ((size_t)((b * NH_ + h) * S_) + q0) * DH_;
        bf16x8 a_q[4];
        #pragma unroll
        for (int ks = 0; ks < 4; ks++)
            a_q[ks] = *(const bf16x8*)(Qp + (size_t)lrow * DH_ + ks * 32 + lhi * 8);
        asm volatile("s_waitcnt vmcnt(0)" ::: "memory");
        __builtin_amdgcn_s_barrier();

        float m_run = -1e30f, l_run = 0.f;
        f32x4 o_acc[8] = {};
        int cur = 0;

        for (int t = 0; t < ntiles; t++) {
            const bool has_next = (t + 1 < ntiles);
            #pragma unroll
            for (int i = 0; i < 4; i++) {
                const int ci = wave * 4 + i;
                const int r  = ci * 8 + vrow_l;
                __builtin_amdgcn_global_load_lds(
                    (gptr_t)(Vbase + (size_t)r * (S_ * 2) + t * (KVB * 2)
                             + (vcol ^ ((r & 7) << 4))),
                    (lptr_t)(lds_vt + ci * 1024), 16, 0, 0);
            }
            if (has_next) {
                const char* ksrc = Kbase + (size_t)(t + 1) * 16384;
                #pragma unroll
                for (int i = 0; i < 4; i++) {
                    const int ci = wave * 4 + i;
                    const int r  = ci * 4 + lhi;
                    __builtin_amdgcn_global_load_lds(
                        (gptr_t)(ksrc + (size_t)r * 256 + (kcol ^ ((r & 7) << 4))),
                        (lptr_t)(lds_kt[cur ^ 1] + ci * 1024), 16, 0, 0);
                }
            }
            f32x4 s_acc[4] = {};
            #pragma unroll
            for (int sub = 0; sub < 4; sub++) {
                const int r = sub * 16 + lrow;
                #pragma unroll
                for (int ks = 0; ks < 4; ks++) {
                    const bf16x8 a_k = *(const bf16x8*)(
                        lds_kt[cur] + r * 256 + ((ks * 64 + lhi * 16) ^ ((r & 7) << 4)));
                    s_acc[sub] = __builtin_amdgcn_mfma_f32_16x16x32_bf16(
                        a_k, a_q[ks], s_acc[sub], 0, 0, 0);
                }
            }
            float pv[16];
            float mx = -1e30f;
            if (!has_next) {
                #pragma unroll
                for (int sub = 0; sub < 4; sub++)
                    #pragma unroll
                    for (int r = 0; r < 4; r++) {
                        const int kvg = t * KVB + sub * 16 + lhi * 4 + r;
                        float sv = s_acc[sub][r] * SCALE_;
                        if (kvg > q_glob) sv = -1e30f;
                        pv[sub * 4 + r] = sv;
                        mx = fmaxf(mx, sv);
                    }
            } else {
                #pragma unroll
                for (int sub = 0; sub < 4; sub++)
                    #pragma unroll
                    for (int r = 0; r < 4; r++) {
                        const float sv = s_acc[sub][r] * SCALE_;
                        pv[sub * 4 + r] = sv;
                        mx = fmaxf(mx, sv);
                    }
            }
            mx = fmaxf(mx, __shfl_xor(mx, 16));
            mx = fmaxf(mx, __shfl_xor(mx, 32));
            const float mnew = fmaxf(m_run, mx);
            const float scale = __expf(m_run - mnew);
            m_run = mnew;
            float sm = 0.f;
            #pragma unroll
            for (int i = 0; i < 16; i++) {
                const float e = __expf(pv[i] - mnew);
                pv[i] = e;
                sm += e;
            }
            sm += __shfl_xor(sm, 16);
            sm += __shfl_xor(sm, 32);
            l_run = l_run * scale + sm;
            #pragma unroll
            for (int d = 0; d < 8; d++) {
                o_acc[d][0] *= scale; o_acc[d][1] *= scale;
                o_acc[d][2] *= scale; o_acc[d][3] *= scale;
            }
            #pragma unroll
            for (int sub = 0; sub < 4; sub++) {
                const int off = (lrow * 128 + sub * 32 + lhi * 8) ^ ((lrow & 7) << 4);
                *reinterpret_cast<uint2*>(myp + off) = make_uint2(
                    pack2bf(pv[sub * 4 + 0], pv[sub * 4 + 1]),
                    pack2bf(pv[sub * 4 + 2], pv[sub * 4 + 3]));
            }
            bf16x8 a_p[2];
            #pragma unroll
            for (int frag = 0; frag < 2; frag++) {
                const int off = (lrow * 128 + frag * 64 + lhi * 16) ^ ((lrow & 7) << 4);
                a_p[frag] = *reinterpret_cast<const bf16x8*>(myp + off);
            }
            if (has_next) asm volatile("s_waitcnt vmcnt(4)" ::: "memory");
            else          asm volatile("s_waitcnt vmcnt(0)" ::: "memory");
            __builtin_amdgcn_s_barrier();
            #pragma unroll
            for (int d = 0; d < 8; d++) {
                const int r = d * 16 + lrow;
                #pragma unroll
                for (int frag = 0; frag < 2; frag++) {
                    const bf16x8 a_v = *(const bf16x8*)(
                        lds_vt + r * 128 + ((frag * 64 + lhi * 16) ^ ((r & 7) << 4)));
                    o_acc[d] = __builtin_amdgcn_mfma_f32_16x16x32_bf16(
                        a_v, a_p[frag], o_acc[d], 0, 0, 0);
                }
            }
            asm volatile("s_waitcnt vmcnt(0)" ::: "memory");
            __builtin_amdgcn_s_barrier();
            cur ^= 1;
        }
        const float inv = 1.f / l_run;
        const size_t row = (size_t)b * S_ + q0 + lrow;
        #pragma unroll
        for (int d = 0; d < 8; d++) {
            unsigned short* dst = ctx + row * (NH_ * DH_) + h * DH_ + d * 16 + lhi * 4;
            *reinterpret_cast<uint2*>(dst) = make_uint2(
                pack2bf(o_acc[d][0] * inv, o_acc[d][1] * inv),
                pack2bf(o_acc[d][2] * inv, o_acc[d][3] * inv));
        }
    }
}

// --------------------------------------------------------------------------
extern "C" void kernel_launch(void* const* d_in, const int* in_sizes, int n_in,
                              void* d_out, int out_size, void* d_ws, size_t ws_size,
                              hipStream_t stream)
{
    const float* hidden  = (const float*)d_in[0];
    const int*   pos_ids = (const int*)d_in[1];
    const float* W_qkv   = (const float*)d_in[2];
    const float* b_qkv   = (const float*)d_in[3];
    const float* W_dense = (const float*)d_in[4];
    float* out = (float*)d_out;

    char* ws = (char*)d_ws;
    unsigned short* Xbf = (unsigned short*)(ws);                  // 16 MB
    unsigned short* Wqt = (unsigned short*)(ws + 16777216);       // 36 MB [4608][4096]
    unsigned short* Wdt = (unsigned short*)(ws + 54525952);       // 32 MB [4096][4096]
    float2*         ctab= (float2*)        (ws + 88080384);       // 512 KB [2048][32]
    unsigned short* Qh  = (unsigned short*)(ws + 125829120);      // 16 MB
    unsigned short* Kh  = (unsigned short*)(ws + 142606336);      //  1 MB
    unsigned short* Vt  = (unsigned short*)(ws + 143654912);      //  1 MB
    unsigned short* Ctx = (unsigned short*)(ws + 144703488);      // 16 MB

    const int M = B_ * S_;   // 2048

    // 1. hidden -> bf16; rope table
    k_f32_to_bf16<<<(M * H_ / 4 + 255) / 256, 256, 0, stream>>>(hidden, Xbf, M * H_ / 4);
    k_rope_tab<<<(M * 32 + 255) / 256, 256, 0, stream>>>(pos_ids, ctab);
    // 2. weight transposes (fp32 [K][N] -> bf16 [N][K]), 64x64 vectorized
    k_transpose_bf16<<<dim3(NQKV_ / 64, H_ / 64), 256, 0, stream>>>(W_qkv, Wqt, H_, NQKV_);
    k_transpose_bf16<<<dim3(H_ / 64, H_ / 64), 256, 0, stream>>>(W_dense, Wdt, H_, H_);
    // 3. QKV projection + fused bias/RoPE/reorg -> Qh, Kh, Vt
    k_gemm<1><<<dim3(NQKV_ / 128, M / 128), 256, 0, stream>>>(
        Xbf, Wqt, b_qkv, nullptr, ctab, Qh, Kh, Vt, M, NQKV_, H_);
    // 4. causal GQA attention -> ctx bf16 (512 blocks, 2/CU, balanced pairs)
    k_attn<<<B_ * NH_ * 8, 256, 0, stream>>>(Qh, Kh, Vt, Ctx);
    // 5. dense projection: out = ctx @ W_dense
    k_gemm<0><<<dim3(H_ / 128, M / 128), 256, 0, stream>>>(
        Ctx, Wdt, nullptr, out, nullptr, nullptr, nullptr, nullptr, M, H_, H_);
}